// Round 5
// baseline (929.569 us; speedup 1.0000x reference)
//
#include <hip/hip_runtime.h>

#define DIN   128
#define DMID  256
#define DOUT  128
#define VNUM  50000

typedef __attribute__((ext_vector_type(8))) __bf16 bf16x8;
typedef __attribute__((ext_vector_type(4))) float  f32x4;

// ---- conversions (native HW cvt, RNE) ----
static __device__ __forceinline__ unsigned short b16(float f) {
  union { __bf16 b; unsigned short u; } r; r.b = (__bf16)f; return r.u;
}
static __device__ __forceinline__ unsigned pk2(float lo, float hi) {
  union { __bf16 b[2]; unsigned u; } r;
  r.b[0] = (__bf16)lo; r.b[1] = (__bf16)hi;
  return r.u;
}
// ---- order-preserving monotone maps ----
static __device__ __forceinline__ unsigned unflip_bits(unsigned m) {
  unsigned mask = ((int)m < 0) ? 0x80000000u : 0xFFFFFFFFu;
  return m ^ mask;
}
// flipped u16 -> flipped u32 of same bf16 widened to f32
static __device__ __forceinline__ unsigned flip32_from16(unsigned m) {
  return (m << 16) | ((m & 0x8000u) ? 0u : 0xFFFFu);
}

// ---------------------------------------------------------------------------
// Sort machinery
// ---------------------------------------------------------------------------
__global__ void k_hist(const int* __restrict__ vid, int* __restrict__ counts, int E) {
  int i = blockIdx.x * blockDim.x + threadIdx.x;
  if (i < E) atomicAdd(counts + vid[i], 1);
}

__global__ __launch_bounds__(1024) void k_scan(int* __restrict__ cursor, int V) {
  __shared__ int wsum[16];
  const int tid = threadIdx.x, lane = tid & 63, wv = tid >> 6;
  int carry = 0;
  for (int base = 0; base < V; base += 1024) {
    const int idx = base + tid;
    const int c = (idx < V) ? cursor[idx] : 0;
    int s = c;
#pragma unroll
    for (int d = 1; d < 64; d <<= 1) {
      int t = __shfl_up(s, d, 64);
      if (lane >= d) s += t;
    }
    if (lane == 63) wsum[wv] = s;
    __syncthreads();
    if (wv == 0 && lane < 16) {
      int ws = wsum[lane];
#pragma unroll
      for (int d = 1; d < 16; d <<= 1) {
        int t = __shfl_up(ws, d, 16);
        if (lane >= d) ws += t;
      }
      wsum[lane] = ws;
    }
    __syncthreads();
    const int woff = (wv == 0) ? 0 : wsum[wv - 1];
    if (idx < V) cursor[idx] = carry + woff + (s - c);
    carry += wsum[15];
    __syncthreads();
  }
}

__global__ void k_scatter(const int* __restrict__ vid, int* __restrict__ cursor,
                          int* __restrict__ sorted, int E) {
  int i = blockIdx.x * blockDim.x + threadIdx.x;
  if (i < E) {
    int v = vid[i];
    int p = atomicAdd(cursor + v, 1);
    sorted[p] = i;
  }
}

// ---------------------------------------------------------------------------
// Kernel 1: GEMM1 over sorted edges; epilogue = column-major LDS tile +
// flat 64-row walk (2 threads/col) with uniform ballot-mask run boundaries.
// Block 512 (8 waves); wave w owns cols [w*32, w*32+32).
// ---------------------------------------------------------------------------
__global__ __launch_bounds__(512, 6) void k_gemm1_max(
    const float* __restrict__ x, const int* __restrict__ vid,
    const int* __restrict__ sorted, const float* __restrict__ W1,
    const float* __restrict__ b1, unsigned* __restrict__ zu, int ntiles) {
  __shared__ unsigned short lx[64 * 136];   // x tile bf16 (row-major)
  __shared__ unsigned short zt[256 * 70];   // z tile, flipped bf16, [col][row]
  __shared__ int lvid[64];

  const int tid  = threadIdx.x;
  const int lane = tid & 63;
  const int w    = tid >> 6;       // 0..7
  const int l15  = lane & 15;
  const int l4   = lane >> 4;
  const int row8 = tid >> 3;       // staging: 8 threads per row
  const int s8   = tid & 7;        // 16 floats each

  // W1 fragments + bias for this wave's 32 cols
  bf16x8 bfrag[4][2];
  float  bias[2];
#pragma unroll
  for (int ni = 0; ni < 2; ++ni) {
    const int col = w * 32 + ni * 16 + l15;
    bias[ni] = b1[col];
#pragma unroll
    for (int kk = 0; kk < 4; ++kk) {
      union { bf16x8 v; unsigned short u[8]; } tmp;
#pragma unroll
      for (int j = 0; j < 8; ++j)
        tmp.u[j] = b16(W1[(kk * 32 + l4 * 8 + j) * DMID + col]);
      bfrag[kk][ni] = tmp.v;
    }
  }

  for (int t = blockIdx.x; t < ntiles; t += gridDim.x) {
    // ---- stage x tile + vids ----
    if (tid < 64) lvid[tid] = vid[sorted[t * 64 + tid]];
    {
      const int eid = sorted[t * 64 + row8];
      const float4* src =
          reinterpret_cast<const float4*>(x + (size_t)eid * DIN + s8 * 16);
#pragma unroll
      for (int i = 0; i < 4; ++i) {
        float4 v = src[i];
        uint2 o = { pk2(v.x, v.y), pk2(v.z, v.w) };
        *reinterpret_cast<uint2*>(&lx[row8 * 136 + s8 * 16 + i * 4]) = o;
      }
    }
    __syncthreads();

    // uniform run-end mask (bit r = row r ends a vid run)
    const int myv = lvid[lane];
    const int nv  = (lane == 63) ? (myv ^ 1) : lvid[lane + 1];
    const unsigned long long emask = __ballot(myv != nv);
    const bool contOpen = (lvid[31] == lvid[32]);

    // ---- MFMA: 64 rows x 32 cols per wave, K=128 ----
    f32x4 acc[4][2];
#pragma unroll
    for (int mi = 0; mi < 4; ++mi)
#pragma unroll
      for (int ni = 0; ni < 2; ++ni)
        acc[mi][ni] = (f32x4){bias[ni], bias[ni], bias[ni], bias[ni]};
#pragma unroll
    for (int kk = 0; kk < 4; ++kk) {
      bf16x8 a[4];
#pragma unroll
      for (int mi = 0; mi < 4; ++mi)
        a[mi] = *reinterpret_cast<const bf16x8*>(
            &lx[(mi * 16 + l15) * 136 + kk * 32 + l4 * 8]);
#pragma unroll
      for (int mi = 0; mi < 4; ++mi)
#pragma unroll
        for (int ni = 0; ni < 2; ++ni)
          acc[mi][ni] = __builtin_amdgcn_mfma_f32_16x16x32_bf16(
              a[mi], bfrag[kk][ni], acc[mi][ni], 0, 0, 0);
    }

    // ---- pack acc -> zt (flipped bf16, column-major) ----
    {
      unsigned* ztw = reinterpret_cast<unsigned*>(zt);
#pragma unroll
      for (int ni = 0; ni < 2; ++ni) {
        const int col = w * 32 + ni * 16 + l15;
        const int cb  = col * 35 + l4 * 2;
#pragma unroll
        for (int mi = 0; mi < 4; ++mi)
#pragma unroll
          for (int p = 0; p < 2; ++p) {
            unsigned tpk = pk2(acc[mi][ni][2 * p], acc[mi][ni][2 * p + 1]);
            unsigned mflip = 0x80008000u + ((tpk >> 15) & 0x00010001u) * 0x7FFFu;
            ztw[cb + mi * 8 + p] = tpk ^ mflip;
          }
      }
    }
    __syncthreads();

    // ---- flat walk: 2 threads per column, 32 rows each ----
    {
      const int col = tid & 255;
      const int h   = tid >> 8;
      const unsigned* zc = reinterpret_cast<const unsigned*>(&zt[col * 70 + h * 32]);
      unsigned cur = 0;
      bool first = true;
#pragma unroll
      for (int p = 0; p < 16; ++p) {
        const unsigned pr = zc[p];
#pragma unroll
        for (int j = 0; j < 2; ++j) {
          const unsigned val = j ? (pr >> 16) : (pr & 0xFFFFu);
          cur = val > cur ? val : cur;
          const int row = h * 32 + p * 2 + j;
          if ((emask >> row) & 1) {
            const int v = lvid[row];
            const unsigned enc = flip32_from16(cur);
            unsigned* ad = zu + (size_t)v * DMID + col;
            if (row == 63 || (first && (h == 0 || contOpen))) atomicMax(ad, enc);
            else *ad = enc;
            cur = 0; first = false;
          }
        }
      }
      if (h == 0 && !((emask >> 31) & 1)) {  // trailing open run in top half
        const int v = lvid[31];
        atomicMax(zu + (size_t)v * DMID + col, flip32_from16(cur));
      }
    }
    __syncthreads();
  }
}

// ---------------------------------------------------------------------------
// Kernel Y: Y = unflip(zu) @ W2b  (V x 128). Block 256, wave 2x2.
// ---------------------------------------------------------------------------
__global__ __launch_bounds__(256) void k_ymm(
    const unsigned* __restrict__ zu, const float* __restrict__ W2,
    float* __restrict__ Y, int ntiles) {
  extern __shared__ unsigned short sm[];
  unsigned short* w2bt = sm;               // [128][264]
  unsigned short* za   = sm + 128 * 264;   // [64][264]

  const int tid  = threadIdx.x;
  const int lane = tid & 63;
  const int w    = tid >> 6;
  const int wr   = w >> 1, wc = w & 1;
  const int l15  = lane & 15, l4 = lane >> 4;

  {
    const int n = tid & 127, kh = tid >> 7;
    for (int k = kh * 128; k < kh * 128 + 128; ++k)
      w2bt[n * 264 + k] = b16(W2[(size_t)(DIN + k) * DOUT + n]);
  }
  __syncthreads();

  for (int t = blockIdx.x; t < ntiles; t += gridDim.x) {
    {
      const int row = tid >> 2, q = tid & 3;
      const int v = t * 64 + row;
      unsigned short* dz = &za[row * 264 + q * 64];
      if (v < VNUM) {
        const uint4* sz = reinterpret_cast<const uint4*>(zu + (size_t)v * DMID + q * 64);
#pragma unroll
        for (int i = 0; i < 16; ++i) {
          uint4 m = sz[i];
          ushort4 o = { (unsigned short)(unflip_bits(m.x) >> 16),
                        (unsigned short)(unflip_bits(m.y) >> 16),
                        (unsigned short)(unflip_bits(m.z) >> 16),
                        (unsigned short)(unflip_bits(m.w) >> 16) };
          *reinterpret_cast<ushort4*>(dz + i * 4) = o;
        }
      } else {
        ushort4 zo = {0, 0, 0, 0};
#pragma unroll
        for (int i = 0; i < 16; ++i) *reinterpret_cast<ushort4*>(dz + i * 4) = zo;
      }
    }
    __syncthreads();

    f32x4 acc[2][4];
#pragma unroll
    for (int mi = 0; mi < 2; ++mi)
#pragma unroll
      for (int ni = 0; ni < 4; ++ni) acc[mi][ni] = (f32x4){0.f, 0.f, 0.f, 0.f};

#pragma unroll
    for (int kk = 0; kk < 8; ++kk) {
      bf16x8 a[2], b[4];
#pragma unroll
      for (int mi = 0; mi < 2; ++mi)
        a[mi] = *reinterpret_cast<const bf16x8*>(
            &za[(wr * 32 + mi * 16 + l15) * 264 + kk * 32 + l4 * 8]);
#pragma unroll
      for (int ni = 0; ni < 4; ++ni)
        b[ni] = *reinterpret_cast<const bf16x8*>(
            &w2bt[(wc * 64 + ni * 16 + l15) * 264 + kk * 32 + l4 * 8]);
#pragma unroll
      for (int mi = 0; mi < 2; ++mi)
#pragma unroll
        for (int ni = 0; ni < 4; ++ni)
          acc[mi][ni] = __builtin_amdgcn_mfma_f32_16x16x32_bf16(
              a[mi], b[ni], acc[mi][ni], 0, 0, 0);
    }

#pragma unroll
    for (int mi = 0; mi < 2; ++mi)
#pragma unroll
      for (int r = 0; r < 4; ++r) {
        const int v = t * 64 + wr * 32 + mi * 16 + l4 * 4 + r;
        if (v < VNUM) {
          float* o = Y + (size_t)v * DOUT + wc * 64 + l15;
#pragma unroll
          for (int ni = 0; ni < 4; ++ni) o[ni * 16] = acc[mi][ni][r];
        }
      }
    __syncthreads();
  }
}

// ---------------------------------------------------------------------------
// Kernel 2: out = x @ W2a + Y[vid]  (original edge order). Block 256, wave 2x2.
// ---------------------------------------------------------------------------
__global__ __launch_bounds__(256, 3) void k_gemm2(
    const float* __restrict__ x, const int* __restrict__ vid,
    const float* __restrict__ W2, const float* __restrict__ Y,
    float* __restrict__ out, int ntiles) {
  __shared__ unsigned short w2at[128 * 136];
  __shared__ unsigned short lx[64 * 136];
  __shared__ int lvid[64];

  const int tid  = threadIdx.x;
  const int lane = tid & 63;
  const int w    = tid >> 6;
  const int wr   = w >> 1, wc = w & 1;
  const int l15  = lane & 15, l4 = lane >> 4;

  {
    const int n = tid & 127, kh = tid >> 7;
    for (int k = kh * 64; k < kh * 64 + 64; ++k)
      w2at[n * 136 + k] = b16(W2[(size_t)k * DOUT + n]);
  }
  __syncthreads();

  for (int t = blockIdx.x; t < ntiles; t += gridDim.x) {
    {
      const int row = tid >> 2, q = tid & 3;
      const float4* sx =
          reinterpret_cast<const float4*>(x + (size_t)(t * 64 + row) * DIN + q * 32);
#pragma unroll
      for (int i = 0; i < 8; ++i) {
        float4 v = sx[i];
        uint2 o = { pk2(v.x, v.y), pk2(v.z, v.w) };
        *reinterpret_cast<uint2*>(&lx[row * 136 + q * 32 + i * 4]) = o;
      }
      if (tid < 64) lvid[tid] = vid[t * 64 + tid];
    }
    __syncthreads();

    f32x4 acc[2][4];
#pragma unroll
    for (int mi = 0; mi < 2; ++mi)
#pragma unroll
      for (int ni = 0; ni < 4; ++ni) acc[mi][ni] = (f32x4){0.f, 0.f, 0.f, 0.f};

#pragma unroll
    for (int kk = 0; kk < 4; ++kk) {
      bf16x8 a[2], b[4];
#pragma unroll
      for (int mi = 0; mi < 2; ++mi)
        a[mi] = *reinterpret_cast<const bf16x8*>(
            &lx[(wr * 32 + mi * 16 + l15) * 136 + kk * 32 + l4 * 8]);
#pragma unroll
      for (int ni = 0; ni < 4; ++ni)
        b[ni] = *reinterpret_cast<const bf16x8*>(
            &w2at[(wc * 64 + ni * 16 + l15) * 136 + kk * 32 + l4 * 8]);
#pragma unroll
      for (int mi = 0; mi < 2; ++mi)
#pragma unroll
        for (int ni = 0; ni < 4; ++ni)
          acc[mi][ni] = __builtin_amdgcn_mfma_f32_16x16x32_bf16(
              a[mi], b[ni], acc[mi][ni], 0, 0, 0);
    }

    // epilogue: + Y[vid], fp32 store
#pragma unroll
    for (int mi = 0; mi < 2; ++mi)
#pragma unroll
      for (int r = 0; r < 4; ++r) {
        const int row = wr * 32 + mi * 16 + l4 * 4 + r;
        const float* Yr = Y + (size_t)lvid[row] * DOUT + wc * 64 + l15;
        float* o = out + (size_t)(t * 64 + row) * DOUT + wc * 64 + l15;
#pragma unroll
        for (int ni = 0; ni < 4; ++ni) o[ni * 16] = acc[mi][ni][r] + Yr[ni * 16];
      }
    __syncthreads();
  }
}

// ---------------------------------------------------------------------------
extern "C" void kernel_launch(void* const* d_in, const int* in_sizes, int n_in,
                              void* d_out, int out_size, void* d_ws, size_t ws_size,
                              hipStream_t stream) {
  const float* x   = (const float*)d_in[0];
  const int*   vid = (const int*)d_in[1];
  const float* W1  = (const float*)d_in[2];
  const float* b1  = (const float*)d_in[3];
  const float* W2  = (const float*)d_in[4];
  float* out = (float*)d_out;

  const int E = in_sizes[1];      // 800000 (divisible by 64)
  const int ntiles = E / 64;
  const int ntY = (VNUM + 63) / 64;   // 782

  char* ws = (char*)d_ws;
  unsigned* zu = (unsigned*)ws;                                    // V*256 u32
  int* cnt     = (int*)(ws + (size_t)VNUM * DMID * 4);             // V
  int* sorted  = (int*)(ws + (size_t)VNUM * DMID * 4 + VNUM * 4);  // E
  float* Y     = (float*)(ws + (size_t)VNUM * DMID * 4 + VNUM * 4 + (size_t)E * 4);

  hipMemsetAsync(zu, 0, (size_t)VNUM * DMID * 4 + VNUM * 4, stream);

  k_hist<<<(E + 255) / 256, 256, 0, stream>>>(vid, cnt, E);
  k_scan<<<1, 1024, 0, stream>>>(cnt, VNUM);
  k_scatter<<<(E + 255) / 256, 256, 0, stream>>>(vid, cnt, sorted, E);

  k_gemm1_max<<<2048, 512, 0, stream>>>(x, vid, sorted, W1, b1, zu, ntiles);

  const int smY = (128 * 264 + 64 * 264) * sizeof(unsigned short);
  hipFuncSetAttribute((const void*)k_ymm,
                      hipFuncAttributeMaxDynamicSharedMemorySize, smY);
  k_ymm<<<782, 256, smY, stream>>>(zu, W2, Y, ntY);

  k_gemm2<<<768, 256, 0, stream>>>(x, vid, W2, Y, out, ntiles);
}

// Round 6
// 872.462 us; speedup vs baseline: 1.0655x; 1.0655x over previous
//
#include <hip/hip_runtime.h>

#define DIN   128
#define DMID  256
#define DOUT  128
#define VNUM  50000

typedef __attribute__((ext_vector_type(8))) __bf16 bf16x8;
typedef __attribute__((ext_vector_type(4))) float  f32x4;

// ---- conversions (native HW cvt, RNE) ----
static __device__ __forceinline__ unsigned short b16(float f) {
  union { __bf16 b; unsigned short u; } r; r.b = (__bf16)f; return r.u;
}
static __device__ __forceinline__ unsigned pk2(float lo, float hi) {
  union { __bf16 b[2]; unsigned u; } r;
  r.b[0] = (__bf16)lo; r.b[1] = (__bf16)hi;
  return r.u;
}
// ---- order-preserving monotone maps ----
static __device__ __forceinline__ unsigned unflip_bits(unsigned m) {
  unsigned mask = ((int)m < 0) ? 0x80000000u : 0xFFFFFFFFu;
  return m ^ mask;
}
// flipped u16 -> flipped u32 of same bf16 widened to f32
static __device__ __forceinline__ unsigned flip32_from16(unsigned m) {
  return (m << 16) | ((m & 0x8000u) ? 0u : 0xFFFFu);
}

// ---------------------------------------------------------------------------
// Sort machinery
// ---------------------------------------------------------------------------
__global__ void k_hist(const int* __restrict__ vid, int* __restrict__ counts, int E) {
  int i = blockIdx.x * blockDim.x + threadIdx.x;
  if (i < E) atomicAdd(counts + vid[i], 1);
}

__global__ __launch_bounds__(1024) void k_scan(int* __restrict__ cursor, int V) {
  __shared__ int wsum[16];
  const int tid = threadIdx.x, lane = tid & 63, wv = tid >> 6;
  int carry = 0;
  for (int base = 0; base < V; base += 1024) {
    const int idx = base + tid;
    const int c = (idx < V) ? cursor[idx] : 0;
    int s = c;
#pragma unroll
    for (int d = 1; d < 64; d <<= 1) {
      int t = __shfl_up(s, d, 64);
      if (lane >= d) s += t;
    }
    if (lane == 63) wsum[wv] = s;
    __syncthreads();
    if (wv == 0 && lane < 16) {
      int ws = wsum[lane];
#pragma unroll
      for (int d = 1; d < 16; d <<= 1) {
        int t = __shfl_up(ws, d, 16);
        if (lane >= d) ws += t;
      }
      wsum[lane] = ws;
    }
    __syncthreads();
    const int woff = (wv == 0) ? 0 : wsum[wv - 1];
    if (idx < V) cursor[idx] = carry + woff + (s - c);
    carry += wsum[15];
    __syncthreads();
  }
}

__global__ void k_scatter(const int* __restrict__ vid, int* __restrict__ cursor,
                          int* __restrict__ sorted, int E) {
  int i = blockIdx.x * blockDim.x + threadIdx.x;
  if (i < E) {
    int v = vid[i];
    int p = atomicAdd(cursor + v, 1);
    sorted[p] = i;
  }
}

// ---------------------------------------------------------------------------
// Kernel 1: GEMM1 over sorted edges; epilogue = column-major LDS tile +
// flat 64-row walk (2 threads/col) with uniform ballot-mask run boundaries.
// Block 512 (8 waves); wave w owns cols [w*32, w*32+32).
// NOTE: __launch_bounds__ second arg MUST be 4: live data alone is 64 VGPR
// (bfrag 32 + acc 32); (512,6) caps at ~85 and the compiler spilled to
// scratch (r5: VGPR 40, FETCH 1.26GB, WRITE 417MB, dur 537us).
// ---------------------------------------------------------------------------
__global__ __launch_bounds__(512, 4) void k_gemm1_max(
    const float* __restrict__ x, const int* __restrict__ vid,
    const int* __restrict__ sorted, const float* __restrict__ W1,
    const float* __restrict__ b1, unsigned* __restrict__ zu, int ntiles) {
  __shared__ unsigned short lx[64 * 136];   // x tile bf16 (row-major)
  __shared__ unsigned short zt[256 * 70];   // z tile, flipped bf16, [col][row]
  __shared__ int lvid[64];

  const int tid  = threadIdx.x;
  const int lane = tid & 63;
  const int w    = tid >> 6;       // 0..7
  const int l15  = lane & 15;
  const int l4   = lane >> 4;
  const int row8 = tid >> 3;       // staging: 8 threads per row
  const int s8   = tid & 7;        // 16 floats each

  // W1 fragments + bias for this wave's 32 cols
  bf16x8 bfrag[4][2];
  float  bias[2];
#pragma unroll
  for (int ni = 0; ni < 2; ++ni) {
    const int col = w * 32 + ni * 16 + l15;
    bias[ni] = b1[col];
#pragma unroll
    for (int kk = 0; kk < 4; ++kk) {
      union { bf16x8 v; unsigned short u[8]; } tmp;
#pragma unroll
      for (int j = 0; j < 8; ++j)
        tmp.u[j] = b16(W1[(kk * 32 + l4 * 8 + j) * DMID + col]);
      bfrag[kk][ni] = tmp.v;
    }
  }

  for (int t = blockIdx.x; t < ntiles; t += gridDim.x) {
    // ---- stage x tile + vids ----
    if (tid < 64) lvid[tid] = vid[sorted[t * 64 + tid]];
    {
      const int eid = sorted[t * 64 + row8];
      const float4* src =
          reinterpret_cast<const float4*>(x + (size_t)eid * DIN + s8 * 16);
#pragma unroll
      for (int i = 0; i < 4; ++i) {
        float4 v = src[i];
        uint2 o = { pk2(v.x, v.y), pk2(v.z, v.w) };
        *reinterpret_cast<uint2*>(&lx[row8 * 136 + s8 * 16 + i * 4]) = o;
      }
    }
    __syncthreads();

    // uniform run-end mask (bit r = row r ends a vid run)
    const int myv = lvid[lane];
    const int nv  = (lane == 63) ? (myv ^ 1) : lvid[lane + 1];
    const unsigned long long emask = __ballot(myv != nv);
    const bool contOpen = (lvid[31] == lvid[32]);

    // ---- MFMA: 64 rows x 32 cols per wave, K=128 ----
    f32x4 acc[4][2];
#pragma unroll
    for (int mi = 0; mi < 4; ++mi)
#pragma unroll
      for (int ni = 0; ni < 2; ++ni)
        acc[mi][ni] = (f32x4){bias[ni], bias[ni], bias[ni], bias[ni]};
#pragma unroll
    for (int kk = 0; kk < 4; ++kk) {
      bf16x8 a[4];
#pragma unroll
      for (int mi = 0; mi < 4; ++mi)
        a[mi] = *reinterpret_cast<const bf16x8*>(
            &lx[(mi * 16 + l15) * 136 + kk * 32 + l4 * 8]);
#pragma unroll
      for (int mi = 0; mi < 4; ++mi)
#pragma unroll
        for (int ni = 0; ni < 2; ++ni)
          acc[mi][ni] = __builtin_amdgcn_mfma_f32_16x16x32_bf16(
              a[mi], bfrag[kk][ni], acc[mi][ni], 0, 0, 0);
    }

    // ---- pack acc -> zt (flipped bf16, column-major) ----
    {
      unsigned* ztw = reinterpret_cast<unsigned*>(zt);
#pragma unroll
      for (int ni = 0; ni < 2; ++ni) {
        const int col = w * 32 + ni * 16 + l15;
        const int cb  = col * 35 + l4 * 2;
#pragma unroll
        for (int mi = 0; mi < 4; ++mi)
#pragma unroll
          for (int p = 0; p < 2; ++p) {
            unsigned tpk = pk2(acc[mi][ni][2 * p], acc[mi][ni][2 * p + 1]);
            unsigned mflip = 0x80008000u + ((tpk >> 15) & 0x00010001u) * 0x7FFFu;
            ztw[cb + mi * 8 + p] = tpk ^ mflip;
          }
      }
    }
    __syncthreads();

    // ---- flat walk: 2 threads per column, 32 rows each ----
    {
      const int col = tid & 255;
      const int h   = tid >> 8;
      const unsigned* zc = reinterpret_cast<const unsigned*>(&zt[col * 70 + h * 32]);
      unsigned cur = 0;
      bool first = true;
#pragma unroll
      for (int p = 0; p < 16; ++p) {
        const unsigned pr = zc[p];
#pragma unroll
        for (int j = 0; j < 2; ++j) {
          const unsigned val = j ? (pr >> 16) : (pr & 0xFFFFu);
          cur = val > cur ? val : cur;
          const int row = h * 32 + p * 2 + j;
          if ((emask >> row) & 1) {
            const int v = lvid[row];
            const unsigned enc = flip32_from16(cur);
            unsigned* ad = zu + (size_t)v * DMID + col;
            if (row == 63 || (first && (h == 0 || contOpen))) atomicMax(ad, enc);
            else *ad = enc;
            cur = 0; first = false;
          }
        }
      }
      if (h == 0 && !((emask >> 31) & 1)) {  // trailing open run in top half
        const int v = lvid[31];
        atomicMax(zu + (size_t)v * DMID + col, flip32_from16(cur));
      }
    }
    __syncthreads();
  }
}

// ---------------------------------------------------------------------------
// Kernel Y: Y = unflip(zu) @ W2b  (V x 128). Block 256, wave 2x2.
// ---------------------------------------------------------------------------
__global__ __launch_bounds__(256) void k_ymm(
    const unsigned* __restrict__ zu, const float* __restrict__ W2,
    float* __restrict__ Y, int ntiles) {
  extern __shared__ unsigned short sm[];
  unsigned short* w2bt = sm;               // [128][264]
  unsigned short* za   = sm + 128 * 264;   // [64][264]

  const int tid  = threadIdx.x;
  const int lane = tid & 63;
  const int w    = tid >> 6;
  const int wr   = w >> 1, wc = w & 1;
  const int l15  = lane & 15, l4 = lane >> 4;

  {
    const int n = tid & 127, kh = tid >> 7;
    for (int k = kh * 128; k < kh * 128 + 128; ++k)
      w2bt[n * 264 + k] = b16(W2[(size_t)(DIN + k) * DOUT + n]);
  }
  __syncthreads();

  for (int t = blockIdx.x; t < ntiles; t += gridDim.x) {
    {
      const int row = tid >> 2, q = tid & 3;
      const int v = t * 64 + row;
      unsigned short* dz = &za[row * 264 + q * 64];
      if (v < VNUM) {
        const uint4* sz = reinterpret_cast<const uint4*>(zu + (size_t)v * DMID + q * 64);
#pragma unroll
        for (int i = 0; i < 16; ++i) {
          uint4 m = sz[i];
          ushort4 o = { (unsigned short)(unflip_bits(m.x) >> 16),
                        (unsigned short)(unflip_bits(m.y) >> 16),
                        (unsigned short)(unflip_bits(m.z) >> 16),
                        (unsigned short)(unflip_bits(m.w) >> 16) };
          *reinterpret_cast<ushort4*>(dz + i * 4) = o;
        }
      } else {
        ushort4 zo = {0, 0, 0, 0};
#pragma unroll
        for (int i = 0; i < 16; ++i) *reinterpret_cast<ushort4*>(dz + i * 4) = zo;
      }
    }
    __syncthreads();

    f32x4 acc[2][4];
#pragma unroll
    for (int mi = 0; mi < 2; ++mi)
#pragma unroll
      for (int ni = 0; ni < 4; ++ni) acc[mi][ni] = (f32x4){0.f, 0.f, 0.f, 0.f};

#pragma unroll
    for (int kk = 0; kk < 8; ++kk) {
      bf16x8 a[2], b[4];
#pragma unroll
      for (int mi = 0; mi < 2; ++mi)
        a[mi] = *reinterpret_cast<const bf16x8*>(
            &za[(wr * 32 + mi * 16 + l15) * 264 + kk * 32 + l4 * 8]);
#pragma unroll
      for (int ni = 0; ni < 4; ++ni)
        b[ni] = *reinterpret_cast<const bf16x8*>(
            &w2bt[(wc * 64 + ni * 16 + l15) * 264 + kk * 32 + l4 * 8]);
#pragma unroll
      for (int mi = 0; mi < 2; ++mi)
#pragma unroll
        for (int ni = 0; ni < 4; ++ni)
          acc[mi][ni] = __builtin_amdgcn_mfma_f32_16x16x32_bf16(
              a[mi], b[ni], acc[mi][ni], 0, 0, 0);
    }

#pragma unroll
    for (int mi = 0; mi < 2; ++mi)
#pragma unroll
      for (int r = 0; r < 4; ++r) {
        const int v = t * 64 + wr * 32 + mi * 16 + l4 * 4 + r;
        if (v < VNUM) {
          float* o = Y + (size_t)v * DOUT + wc * 64 + l15;
#pragma unroll
          for (int ni = 0; ni < 4; ++ni) o[ni * 16] = acc[mi][ni][r];
        }
      }
    __syncthreads();
  }
}

// ---------------------------------------------------------------------------
// Kernel 2: out = x @ W2a + Y[vid]  (original edge order). Block 256, wave 2x2.
// ---------------------------------------------------------------------------
__global__ __launch_bounds__(256, 3) void k_gemm2(
    const float* __restrict__ x, const int* __restrict__ vid,
    const float* __restrict__ W2, const float* __restrict__ Y,
    float* __restrict__ out, int ntiles) {
  __shared__ unsigned short w2at[128 * 136];
  __shared__ unsigned short lx[64 * 136];
  __shared__ int lvid[64];

  const int tid  = threadIdx.x;
  const int lane = tid & 63;
  const int w    = tid >> 6;
  const int wr   = w >> 1, wc = w & 1;
  const int l15  = lane & 15, l4 = lane >> 4;

  {
    const int n = tid & 127, kh = tid >> 7;
    for (int k = kh * 64; k < kh * 64 + 64; ++k)
      w2at[n * 136 + k] = b16(W2[(size_t)k * DOUT + n]);
  }
  __syncthreads();

  for (int t = blockIdx.x; t < ntiles; t += gridDim.x) {
    {
      const int row = tid >> 2, q = tid & 3;
      const float4* sx =
          reinterpret_cast<const float4*>(x + (size_t)(t * 64 + row) * DIN + q * 32);
#pragma unroll
      for (int i = 0; i < 8; ++i) {
        float4 v = sx[i];
        uint2 o = { pk2(v.x, v.y), pk2(v.z, v.w) };
        *reinterpret_cast<uint2*>(&lx[row * 136 + q * 32 + i * 4]) = o;
      }
      if (tid < 64) lvid[tid] = vid[t * 64 + tid];
    }
    __syncthreads();

    f32x4 acc[2][4];
#pragma unroll
    for (int mi = 0; mi < 2; ++mi)
#pragma unroll
      for (int ni = 0; ni < 4; ++ni) acc[mi][ni] = (f32x4){0.f, 0.f, 0.f, 0.f};

#pragma unroll
    for (int kk = 0; kk < 4; ++kk) {
      bf16x8 a[2], b[4];
#pragma unroll
      for (int mi = 0; mi < 2; ++mi)
        a[mi] = *reinterpret_cast<const bf16x8*>(
            &lx[(wr * 32 + mi * 16 + l15) * 136 + kk * 32 + l4 * 8]);
#pragma unroll
      for (int ni = 0; ni < 4; ++ni)
        b[ni] = *reinterpret_cast<const bf16x8*>(
            &w2at[(wc * 64 + ni * 16 + l15) * 136 + kk * 32 + l4 * 8]);
#pragma unroll
      for (int mi = 0; mi < 2; ++mi)
#pragma unroll
        for (int ni = 0; ni < 4; ++ni)
          acc[mi][ni] = __builtin_amdgcn_mfma_f32_16x16x32_bf16(
              a[mi], b[ni], acc[mi][ni], 0, 0, 0);
    }

    // epilogue: + Y[vid], fp32 store
#pragma unroll
    for (int mi = 0; mi < 2; ++mi)
#pragma unroll
      for (int r = 0; r < 4; ++r) {
        const int row = wr * 32 + mi * 16 + l4 * 4 + r;
        const float* Yr = Y + (size_t)lvid[row] * DOUT + wc * 64 + l15;
        float* o = out + (size_t)(t * 64 + row) * DOUT + wc * 64 + l15;
#pragma unroll
        for (int ni = 0; ni < 4; ++ni) o[ni * 16] = acc[mi][ni][r] + Yr[ni * 16];
      }
    __syncthreads();
  }
}

// ---------------------------------------------------------------------------
extern "C" void kernel_launch(void* const* d_in, const int* in_sizes, int n_in,
                              void* d_out, int out_size, void* d_ws, size_t ws_size,
                              hipStream_t stream) {
  const float* x   = (const float*)d_in[0];
  const int*   vid = (const int*)d_in[1];
  const float* W1  = (const float*)d_in[2];
  const float* b1  = (const float*)d_in[3];
  const float* W2  = (const float*)d_in[4];
  float* out = (float*)d_out;

  const int E = in_sizes[1];      // 800000 (divisible by 64)
  const int ntiles = E / 64;
  const int ntY = (VNUM + 63) / 64;   // 782

  char* ws = (char*)d_ws;
  unsigned* zu = (unsigned*)ws;                                    // V*256 u32
  int* cnt     = (int*)(ws + (size_t)VNUM * DMID * 4);             // V
  int* sorted  = (int*)(ws + (size_t)VNUM * DMID * 4 + VNUM * 4);  // E
  float* Y     = (float*)(ws + (size_t)VNUM * DMID * 4 + VNUM * 4 + (size_t)E * 4);

  hipMemsetAsync(zu, 0, (size_t)VNUM * DMID * 4 + VNUM * 4, stream);

  k_hist<<<(E + 255) / 256, 256, 0, stream>>>(vid, cnt, E);
  k_scan<<<1, 1024, 0, stream>>>(cnt, VNUM);
  k_scatter<<<(E + 255) / 256, 256, 0, stream>>>(vid, cnt, sorted, E);

  k_gemm1_max<<<2048, 512, 0, stream>>>(x, vid, sorted, W1, b1, zu, ntiles);

  const int smY = (128 * 264 + 64 * 264) * sizeof(unsigned short);
  hipFuncSetAttribute((const void*)k_ymm,
                      hipFuncAttributeMaxDynamicSharedMemorySize, smY);
  k_ymm<<<782, 256, smY, stream>>>(zu, W2, Y, ntY);

  k_gemm2<<<768, 256, 0, stream>>>(x, vid, W2, Y, out, ntiles);
}

// Round 7
// 668.616 us; speedup vs baseline: 1.3903x; 1.3049x over previous
//
#include <hip/hip_runtime.h>

#define DIN   128
#define DMID  256
#define DOUT  128
#define VNUM  50000

typedef __attribute__((ext_vector_type(8))) __bf16 bf16x8;
typedef __attribute__((ext_vector_type(4))) float  f32x4;

// ---- conversions (native HW cvt, RNE) ----
static __device__ __forceinline__ unsigned short b16(float f) {
  union { __bf16 b; unsigned short u; } r; r.b = (__bf16)f; return r.u;
}
static __device__ __forceinline__ unsigned pk2(float lo, float hi) {
  union { __bf16 b[2]; unsigned u; } r;
  r.b[0] = (__bf16)lo; r.b[1] = (__bf16)hi;
  return r.u;
}
// ---- order-preserving monotone maps ----
static __device__ __forceinline__ unsigned unflip_bits(unsigned m) {
  unsigned mask = ((int)m < 0) ? 0x80000000u : 0xFFFFFFFFu;
  return m ^ mask;
}
// flipped u16 -> flipped u32 of same bf16 widened to f32
static __device__ __forceinline__ unsigned flip32_from16(unsigned m) {
  return (m << 16) | ((m & 0x8000u) ? 0u : 0xFFFFu);
}

// ---------------------------------------------------------------------------
// Sort machinery
// ---------------------------------------------------------------------------
__global__ void k_hist(const int* __restrict__ vid, int* __restrict__ counts, int E) {
  int i = blockIdx.x * blockDim.x + threadIdx.x;
  if (i < E) atomicAdd(counts + vid[i], 1);
}

__global__ __launch_bounds__(1024) void k_scan(int* __restrict__ cursor, int V) {
  __shared__ int wsum[16];
  const int tid = threadIdx.x, lane = tid & 63, wv = tid >> 6;
  int carry = 0;
  for (int base = 0; base < V; base += 1024) {
    const int idx = base + tid;
    const int c = (idx < V) ? cursor[idx] : 0;
    int s = c;
#pragma unroll
    for (int d = 1; d < 64; d <<= 1) {
      int t = __shfl_up(s, d, 64);
      if (lane >= d) s += t;
    }
    if (lane == 63) wsum[wv] = s;
    __syncthreads();
    if (wv == 0 && lane < 16) {
      int ws = wsum[lane];
#pragma unroll
      for (int d = 1; d < 16; d <<= 1) {
        int t = __shfl_up(ws, d, 16);
        if (lane >= d) ws += t;
      }
      wsum[lane] = ws;
    }
    __syncthreads();
    const int woff = (wv == 0) ? 0 : wsum[wv - 1];
    if (idx < V) cursor[idx] = carry + woff + (s - c);
    carry += wsum[15];
    __syncthreads();
  }
}

__global__ void k_scatter(const int* __restrict__ vid, int* __restrict__ cursor,
                          int* __restrict__ sorted, int E) {
  int i = blockIdx.x * blockDim.x + threadIdx.x;
  if (i < E) {
    int v = vid[i];
    int p = atomicAdd(cursor + v, 1);
    sorted[p] = i;
  }
}

// ---------------------------------------------------------------------------
// Kernel 1: GEMM1 over sorted edges; epilogue = column-major LDS tile +
// flat 64-row walk (2 threads/col) with uniform ballot-mask run boundaries.
// Block 512 (8 waves); wave w owns cols [w*32, w*32+32).
// NOTE on __launch_bounds__: do NOT pass a min-waves hint. Peak live set is
// ~100+ VGPR (acc 32 + bfrag 32 + a[] 16 + pack/walk temps); with a hint the
// allocator squeezed to 64 (r6) / 40 (r5) and spilled to scratch every tile
// (r6: FETCH 905MB vs 430 ideal, WRITE 302MB vs 85 ideal). LDS (53.8KB) caps
// occupancy at 3 blocks/CU regardless, so low VGPR buys nothing.
// ---------------------------------------------------------------------------
__global__ __launch_bounds__(512) void k_gemm1_max(
    const float* __restrict__ x, const int* __restrict__ vid,
    const int* __restrict__ sorted, const float* __restrict__ W1,
    const float* __restrict__ b1, unsigned* __restrict__ zu, int ntiles) {
  __shared__ unsigned short lx[64 * 136];   // x tile bf16 (row-major)
  __shared__ unsigned short zt[256 * 70];   // z tile, flipped bf16, [col][row]
  __shared__ int lvid[64];

  const int tid  = threadIdx.x;
  const int lane = tid & 63;
  const int w    = tid >> 6;       // 0..7
  const int l15  = lane & 15;
  const int l4   = lane >> 4;
  const int row8 = tid >> 3;       // staging: 8 threads per row
  const int s8   = tid & 7;        // 16 floats each

  // W1 fragments + bias for this wave's 32 cols
  bf16x8 bfrag[4][2];
  float  bias[2];
#pragma unroll
  for (int ni = 0; ni < 2; ++ni) {
    const int col = w * 32 + ni * 16 + l15;
    bias[ni] = b1[col];
#pragma unroll
    for (int kk = 0; kk < 4; ++kk) {
      union { bf16x8 v; unsigned short u[8]; } tmp;
#pragma unroll
      for (int j = 0; j < 8; ++j)
        tmp.u[j] = b16(W1[(kk * 32 + l4 * 8 + j) * DMID + col]);
      bfrag[kk][ni] = tmp.v;
    }
  }

  for (int t = blockIdx.x; t < ntiles; t += gridDim.x) {
    // ---- stage x tile + vids ----
    if (tid < 64) lvid[tid] = vid[sorted[t * 64 + tid]];
    {
      const int eid = sorted[t * 64 + row8];
      const float4* src =
          reinterpret_cast<const float4*>(x + (size_t)eid * DIN + s8 * 16);
#pragma unroll
      for (int i = 0; i < 4; ++i) {
        float4 v = src[i];
        uint2 o = { pk2(v.x, v.y), pk2(v.z, v.w) };
        *reinterpret_cast<uint2*>(&lx[row8 * 136 + s8 * 16 + i * 4]) = o;
      }
    }
    __syncthreads();

    // uniform run-end mask (bit r = row r ends a vid run)
    const int myv = lvid[lane];
    const int nv  = (lane == 63) ? (myv ^ 1) : lvid[lane + 1];
    const unsigned long long emask = __ballot(myv != nv);
    const bool contOpen = (lvid[31] == lvid[32]);

    // ---- MFMA: 64 rows x 32 cols per wave, K=128 ----
    f32x4 acc[4][2];
#pragma unroll
    for (int mi = 0; mi < 4; ++mi)
#pragma unroll
      for (int ni = 0; ni < 2; ++ni)
        acc[mi][ni] = (f32x4){bias[ni], bias[ni], bias[ni], bias[ni]};
#pragma unroll
    for (int kk = 0; kk < 4; ++kk) {
      bf16x8 a[4];
#pragma unroll
      for (int mi = 0; mi < 4; ++mi)
        a[mi] = *reinterpret_cast<const bf16x8*>(
            &lx[(mi * 16 + l15) * 136 + kk * 32 + l4 * 8]);
#pragma unroll
      for (int mi = 0; mi < 4; ++mi)
#pragma unroll
        for (int ni = 0; ni < 2; ++ni)
          acc[mi][ni] = __builtin_amdgcn_mfma_f32_16x16x32_bf16(
              a[mi], bfrag[kk][ni], acc[mi][ni], 0, 0, 0);
    }

    // ---- pack acc -> zt (flipped bf16, column-major) ----
    {
      unsigned* ztw = reinterpret_cast<unsigned*>(zt);
#pragma unroll
      for (int ni = 0; ni < 2; ++ni) {
        const int col = w * 32 + ni * 16 + l15;
        const int cb  = col * 35 + l4 * 2;
#pragma unroll
        for (int mi = 0; mi < 4; ++mi)
#pragma unroll
          for (int p = 0; p < 2; ++p) {
            unsigned tpk = pk2(acc[mi][ni][2 * p], acc[mi][ni][2 * p + 1]);
            unsigned mflip = 0x80008000u + ((tpk >> 15) & 0x00010001u) * 0x7FFFu;
            ztw[cb + mi * 8 + p] = tpk ^ mflip;
          }
      }
    }
    __syncthreads();

    // ---- flat walk: 2 threads per column, 32 rows each ----
    {
      const int col = tid & 255;
      const int h   = tid >> 8;
      const unsigned* zc = reinterpret_cast<const unsigned*>(&zt[col * 70 + h * 32]);
      unsigned cur = 0;
      bool first = true;
#pragma unroll
      for (int p = 0; p < 16; ++p) {
        const unsigned pr = zc[p];
#pragma unroll
        for (int j = 0; j < 2; ++j) {
          const unsigned val = j ? (pr >> 16) : (pr & 0xFFFFu);
          cur = val > cur ? val : cur;
          const int row = h * 32 + p * 2 + j;
          if ((emask >> row) & 1) {
            const int v = lvid[row];
            const unsigned enc = flip32_from16(cur);
            unsigned* ad = zu + (size_t)v * DMID + col;
            if (row == 63 || (first && (h == 0 || contOpen))) atomicMax(ad, enc);
            else *ad = enc;
            cur = 0; first = false;
          }
        }
      }
      if (h == 0 && !((emask >> 31) & 1)) {  // trailing open run in top half
        const int v = lvid[31];
        atomicMax(zu + (size_t)v * DMID + col, flip32_from16(cur));
      }
    }
    __syncthreads();
  }
}

// ---------------------------------------------------------------------------
// Kernel Y: Y = unflip(zu) @ W2b  (V x 128). Block 256, wave 2x2.
// ---------------------------------------------------------------------------
__global__ __launch_bounds__(256) void k_ymm(
    const unsigned* __restrict__ zu, const float* __restrict__ W2,
    float* __restrict__ Y, int ntiles) {
  extern __shared__ unsigned short sm[];
  unsigned short* w2bt = sm;               // [128][264]
  unsigned short* za   = sm + 128 * 264;   // [64][264]

  const int tid  = threadIdx.x;
  const int lane = tid & 63;
  const int w    = tid >> 6;
  const int wr   = w >> 1, wc = w & 1;
  const int l15  = lane & 15, l4 = lane >> 4;

  {
    const int n = tid & 127, kh = tid >> 7;
    for (int k = kh * 128; k < kh * 128 + 128; ++k)
      w2bt[n * 264 + k] = b16(W2[(size_t)(DIN + k) * DOUT + n]);
  }
  __syncthreads();

  for (int t = blockIdx.x; t < ntiles; t += gridDim.x) {
    {
      const int row = tid >> 2, q = tid & 3;
      const int v = t * 64 + row;
      unsigned short* dz = &za[row * 264 + q * 64];
      if (v < VNUM) {
        const uint4* sz = reinterpret_cast<const uint4*>(zu + (size_t)v * DMID + q * 64);
#pragma unroll
        for (int i = 0; i < 16; ++i) {
          uint4 m = sz[i];
          ushort4 o = { (unsigned short)(unflip_bits(m.x) >> 16),
                        (unsigned short)(unflip_bits(m.y) >> 16),
                        (unsigned short)(unflip_bits(m.z) >> 16),
                        (unsigned short)(unflip_bits(m.w) >> 16) };
          *reinterpret_cast<ushort4*>(dz + i * 4) = o;
        }
      } else {
        ushort4 zo = {0, 0, 0, 0};
#pragma unroll
        for (int i = 0; i < 16; ++i) *reinterpret_cast<ushort4*>(dz + i * 4) = zo;
      }
    }
    __syncthreads();

    f32x4 acc[2][4];
#pragma unroll
    for (int mi = 0; mi < 2; ++mi)
#pragma unroll
      for (int ni = 0; ni < 4; ++ni) acc[mi][ni] = (f32x4){0.f, 0.f, 0.f, 0.f};

#pragma unroll
    for (int kk = 0; kk < 8; ++kk) {
      bf16x8 a[2], b[4];
#pragma unroll
      for (int mi = 0; mi < 2; ++mi)
        a[mi] = *reinterpret_cast<const bf16x8*>(
            &za[(wr * 32 + mi * 16 + l15) * 264 + kk * 32 + l4 * 8]);
#pragma unroll
      for (int ni = 0; ni < 4; ++ni)
        b[ni] = *reinterpret_cast<const bf16x8*>(
            &w2bt[(wc * 64 + ni * 16 + l15) * 264 + kk * 32 + l4 * 8]);
#pragma unroll
      for (int mi = 0; mi < 2; ++mi)
#pragma unroll
        for (int ni = 0; ni < 4; ++ni)
          acc[mi][ni] = __builtin_amdgcn_mfma_f32_16x16x32_bf16(
              a[mi], b[ni], acc[mi][ni], 0, 0, 0);
    }

#pragma unroll
    for (int mi = 0; mi < 2; ++mi)
#pragma unroll
      for (int r = 0; r < 4; ++r) {
        const int v = t * 64 + wr * 32 + mi * 16 + l4 * 4 + r;
        if (v < VNUM) {
          float* o = Y + (size_t)v * DOUT + wc * 64 + l15;
#pragma unroll
          for (int ni = 0; ni < 4; ++ni) o[ni * 16] = acc[mi][ni][r];
        }
      }
    __syncthreads();
  }
}

// ---------------------------------------------------------------------------
// Kernel 2: out = x @ W2a + Y[vid]  (original edge order). Block 256, wave 2x2.
// ---------------------------------------------------------------------------
__global__ __launch_bounds__(256, 3) void k_gemm2(
    const float* __restrict__ x, const int* __restrict__ vid,
    const float* __restrict__ W2, const float* __restrict__ Y,
    float* __restrict__ out, int ntiles) {
  __shared__ unsigned short w2at[128 * 136];
  __shared__ unsigned short lx[64 * 136];
  __shared__ int lvid[64];

  const int tid  = threadIdx.x;
  const int lane = tid & 63;
  const int w    = tid >> 6;
  const int wr   = w >> 1, wc = w & 1;
  const int l15  = lane & 15, l4 = lane >> 4;

  {
    const int n = tid & 127, kh = tid >> 7;
    for (int k = kh * 64; k < kh * 64 + 64; ++k)
      w2at[n * 136 + k] = b16(W2[(size_t)k * DOUT + n]);
  }
  __syncthreads();

  for (int t = blockIdx.x; t < ntiles; t += gridDim.x) {
    {
      const int row = tid >> 2, q = tid & 3;
      const float4* sx =
          reinterpret_cast<const float4*>(x + (size_t)(t * 64 + row) * DIN + q * 32);
#pragma unroll
      for (int i = 0; i < 8; ++i) {
        float4 v = sx[i];
        uint2 o = { pk2(v.x, v.y), pk2(v.z, v.w) };
        *reinterpret_cast<uint2*>(&lx[row * 136 + q * 32 + i * 4]) = o;
      }
      if (tid < 64) lvid[tid] = vid[t * 64 + tid];
    }
    __syncthreads();

    f32x4 acc[2][4];
#pragma unroll
    for (int mi = 0; mi < 2; ++mi)
#pragma unroll
      for (int ni = 0; ni < 4; ++ni) acc[mi][ni] = (f32x4){0.f, 0.f, 0.f, 0.f};

#pragma unroll
    for (int kk = 0; kk < 4; ++kk) {
      bf16x8 a[2], b[4];
#pragma unroll
      for (int mi = 0; mi < 2; ++mi)
        a[mi] = *reinterpret_cast<const bf16x8*>(
            &lx[(wr * 32 + mi * 16 + l15) * 136 + kk * 32 + l4 * 8]);
#pragma unroll
      for (int ni = 0; ni < 4; ++ni)
        b[ni] = *reinterpret_cast<const bf16x8*>(
            &w2at[(wc * 64 + ni * 16 + l15) * 136 + kk * 32 + l4 * 8]);
#pragma unroll
      for (int mi = 0; mi < 2; ++mi)
#pragma unroll
        for (int ni = 0; ni < 4; ++ni)
          acc[mi][ni] = __builtin_amdgcn_mfma_f32_16x16x32_bf16(
              a[mi], b[ni], acc[mi][ni], 0, 0, 0);
    }

    // epilogue: + Y[vid], fp32 store
#pragma unroll
    for (int mi = 0; mi < 2; ++mi)
#pragma unroll
      for (int r = 0; r < 4; ++r) {
        const int row = wr * 32 + mi * 16 + l4 * 4 + r;
        const float* Yr = Y + (size_t)lvid[row] * DOUT + wc * 64 + l15;
        float* o = out + (size_t)(t * 64 + row) * DOUT + wc * 64 + l15;
#pragma unroll
        for (int ni = 0; ni < 4; ++ni) o[ni * 16] = acc[mi][ni][r] + Yr[ni * 16];
      }
    __syncthreads();
  }
}

// ---------------------------------------------------------------------------
extern "C" void kernel_launch(void* const* d_in, const int* in_sizes, int n_in,
                              void* d_out, int out_size, void* d_ws, size_t ws_size,
                              hipStream_t stream) {
  const float* x   = (const float*)d_in[0];
  const int*   vid = (const int*)d_in[1];
  const float* W1  = (const float*)d_in[2];
  const float* b1  = (const float*)d_in[3];
  const float* W2  = (const float*)d_in[4];
  float* out = (float*)d_out;

  const int E = in_sizes[1];      // 800000 (divisible by 64)
  const int ntiles = E / 64;
  const int ntY = (VNUM + 63) / 64;   // 782

  char* ws = (char*)d_ws;
  unsigned* zu = (unsigned*)ws;                                    // V*256 u32
  int* cnt     = (int*)(ws + (size_t)VNUM * DMID * 4);             // V
  int* sorted  = (int*)(ws + (size_t)VNUM * DMID * 4 + VNUM * 4);  // E
  float* Y     = (float*)(ws + (size_t)VNUM * DMID * 4 + VNUM * 4 + (size_t)E * 4);

  hipMemsetAsync(zu, 0, (size_t)VNUM * DMID * 4 + VNUM * 4, stream);

  k_hist<<<(E + 255) / 256, 256, 0, stream>>>(vid, cnt, E);
  k_scan<<<1, 1024, 0, stream>>>(cnt, VNUM);
  k_scatter<<<(E + 255) / 256, 256, 0, stream>>>(vid, cnt, sorted, E);

  k_gemm1_max<<<2048, 512, 0, stream>>>(x, vid, sorted, W1, b1, zu, ntiles);

  const int smY = (128 * 264 + 64 * 264) * sizeof(unsigned short);
  hipFuncSetAttribute((const void*)k_ymm,
                      hipFuncAttributeMaxDynamicSharedMemorySize, smY);
  k_ymm<<<782, 256, smY, stream>>>(zu, W2, Y, ntY);

  k_gemm2<<<768, 256, 0, stream>>>(x, vid, W2, Y, out, ntiles);
}

// Round 8
// 608.381 us; speedup vs baseline: 1.5279x; 1.0990x over previous
//
#include <hip/hip_runtime.h>

#define DIN   128
#define DMID  256
#define DOUT  128
#define VNUM  50000

typedef __attribute__((ext_vector_type(8))) __bf16 bf16x8;
typedef __attribute__((ext_vector_type(4))) float  f32x4;

// ---- conversions (native HW cvt, RNE) ----
static __device__ __forceinline__ unsigned short b16(float f) {
  union { __bf16 b; unsigned short u; } r; r.b = (__bf16)f; return r.u;
}
static __device__ __forceinline__ unsigned pk2(float lo, float hi) {
  union { __bf16 b[2]; unsigned u; } r;
  r.b[0] = (__bf16)lo; r.b[1] = (__bf16)hi;
  return r.u;
}
// ---- order-preserving monotone maps ----
static __device__ __forceinline__ unsigned unflip_bits(unsigned m) {
  unsigned mask = ((int)m < 0) ? 0x80000000u : 0xFFFFFFFFu;
  return m ^ mask;
}
// flipped u16 -> flipped u32 of same bf16 widened to f32
static __device__ __forceinline__ unsigned flip32_from16(unsigned m) {
  return (m << 16) | ((m & 0x8000u) ? 0u : 0xFFFFu);
}

// ---------------------------------------------------------------------------
// Sort machinery: hist -> (3-kernel multi-block scan) -> scatter
// ---------------------------------------------------------------------------
__global__ void k_hist(const int* __restrict__ vid, int* __restrict__ counts, int E) {
  int i = blockIdx.x * blockDim.x + threadIdx.x;
  if (i < E) atomicAdd(counts + vid[i], 1);
}

// per-block reduce of 256 counts -> bsum[block]
__global__ __launch_bounds__(256) void k_scan_red(
    const int* __restrict__ cnt, int* __restrict__ bsum, int V) {
  __shared__ int ws[4];
  const int i = blockIdx.x * 256 + threadIdx.x;
  int c = (i < V) ? cnt[i] : 0;
#pragma unroll
  for (int d = 1; d < 64; d <<= 1) c += __shfl_xor(c, d);
  if ((threadIdx.x & 63) == 0) ws[threadIdx.x >> 6] = c;
  __syncthreads();
  if (threadIdx.x == 0) bsum[blockIdx.x] = ws[0] + ws[1] + ws[2] + ws[3];
}

// single-block exclusive scan of nb (<=256) block sums, in place
__global__ __launch_bounds__(256) void k_scan_top(int* __restrict__ bsum, int nb) {
  __shared__ int ws[4];
  const int tid = threadIdx.x, lane = tid & 63, wv = tid >> 6;
  int c = (tid < nb) ? bsum[tid] : 0;
  int s = c;
#pragma unroll
  for (int d = 1; d < 64; d <<= 1) {
    int u = __shfl_up(s, d, 64);
    if (lane >= d) s += u;
  }
  if (lane == 63) ws[wv] = s;
  __syncthreads();
  int off = 0;
  for (int k = 0; k < wv; ++k) off += ws[k];
  if (tid < nb) bsum[tid] = off + (s - c);
}

// per-block exclusive scan + block offset; cursor updated in place
__global__ __launch_bounds__(256) void k_scan_fix(
    int* __restrict__ cursor, const int* __restrict__ bsum, int V) {
  __shared__ int ws[4];
  const int i = blockIdx.x * 256 + threadIdx.x;
  const int lane = threadIdx.x & 63, wv = threadIdx.x >> 6;
  int c = (i < V) ? cursor[i] : 0;
  int s = c;
#pragma unroll
  for (int d = 1; d < 64; d <<= 1) {
    int u = __shfl_up(s, d, 64);
    if (lane >= d) s += u;
  }
  if (lane == 63) ws[wv] = s;
  __syncthreads();
  int off = bsum[blockIdx.x];
  for (int k = 0; k < wv; ++k) off += ws[k];
  if (i < V) cursor[i] = off + (s - c);
}

__global__ void k_scatter(const int* __restrict__ vid, int* __restrict__ cursor,
                          int* __restrict__ sorted, int E) {
  int i = blockIdx.x * blockDim.x + threadIdx.x;
  if (i < E) {
    int v = vid[i];
    int p = atomicAdd(cursor + v, 1);
    sorted[p] = i;
  }
}

// ---------------------------------------------------------------------------
// Kernel 1: GEMM1 over sorted edges; 2 barriers/tile, software-pipelined:
//   [emask; MFMA; pack->zt] bar [issue next-tile loads; walk zt->zu; cvt+write]
// bar. The walk hides the next tile's gather latency; the stage hides the
// walk's scattered-store drain.
// NOTE: NO min-waves hint in __launch_bounds__ — peak live set ~120 VGPR;
// hints of 4/6 squeezed the allocator to 64/40 VGPR and spilled to scratch
// every tile (r5/r6: FETCH 0.9-1.3GB vs 430MB ideal).
// ---------------------------------------------------------------------------
__global__ __launch_bounds__(512) void k_gemm1_max(
    const float* __restrict__ x, const int* __restrict__ vid,
    const int* __restrict__ sorted, const float* __restrict__ W1,
    const float* __restrict__ b1, unsigned* __restrict__ zu, int ntiles) {
  __shared__ unsigned short lx[64 * 136];   // x tile bf16 (row-major)
  __shared__ unsigned short zt[256 * 70];   // z tile, flipped bf16, [col][row]
  __shared__ int lvid[2][64];

  const int tid  = threadIdx.x;
  const int lane = tid & 63;
  const int w    = tid >> 6;       // 0..7
  const int l15  = lane & 15;
  const int l4   = lane >> 4;
  const int row8 = tid >> 3;       // staging: 8 threads per row
  const int s8   = tid & 7;        // 16 floats each
  const int G    = gridDim.x;

  // W1 fragments + bias for this wave's 32 cols
  bf16x8 bfrag[4][2];
  float  bias[2];
#pragma unroll
  for (int ni = 0; ni < 2; ++ni) {
    const int col = w * 32 + ni * 16 + l15;
    bias[ni] = b1[col];
#pragma unroll
    for (int kk = 0; kk < 4; ++kk) {
      union { bf16x8 v; unsigned short u[8]; } tmp;
#pragma unroll
      for (int j = 0; j < 8; ++j)
        tmp.u[j] = b16(W1[(kk * 32 + l4 * 8 + j) * DMID + col]);
      bfrag[kk][ni] = tmp.v;
    }
  }

  const int t0 = blockIdx.x;
  if (t0 >= ntiles) return;

  // ---- prologue: stage tile t0 ----
  {
    if (tid < 64) lvid[0][tid] = vid[sorted[t0 * 64 + tid]];
    const int eid = sorted[t0 * 64 + row8];
    const float4* src =
        reinterpret_cast<const float4*>(x + (size_t)eid * DIN + s8 * 16);
#pragma unroll
    for (int i = 0; i < 4; ++i) {
      float4 v = src[i];
      uint2 o = { pk2(v.x, v.y), pk2(v.z, v.w) };
      *reinterpret_cast<uint2*>(&lx[row8 * 136 + s8 * 16 + i * 4]) = o;
    }
  }
  __syncthreads();

  int cur = 0;
  for (int t = t0; t < ntiles; t += G, cur ^= 1) {
    const int tn = t + G;
    const bool more = (tn < ntiles);
    // issue next-tile index loads early (covered by MFMA+pack)
    int eidN = 0, sidN = 0;
    if (more) {
      eidN = sorted[tn * 64 + row8];
      if (tid < 64) sidN = sorted[tn * 64 + tid];
    }

    // uniform run-end mask (bit r = row r ends a vid run)
    const int myv = lvid[cur][lane];
    const int nv  = (lane == 63) ? (myv ^ 1) : lvid[cur][lane + 1];
    const unsigned long long emask = __ballot(myv != nv);
    const bool contOpen = (lvid[cur][31] == lvid[cur][32]);

    // ---- MFMA: 64 rows x 32 cols per wave, K=128 ----
    f32x4 acc[4][2];
#pragma unroll
    for (int mi = 0; mi < 4; ++mi)
#pragma unroll
      for (int ni = 0; ni < 2; ++ni)
        acc[mi][ni] = (f32x4){bias[ni], bias[ni], bias[ni], bias[ni]};
#pragma unroll
    for (int kk = 0; kk < 4; ++kk) {
      bf16x8 a[4];
#pragma unroll
      for (int mi = 0; mi < 4; ++mi)
        a[mi] = *reinterpret_cast<const bf16x8*>(
            &lx[(mi * 16 + l15) * 136 + kk * 32 + l4 * 8]);
#pragma unroll
      for (int mi = 0; mi < 4; ++mi)
#pragma unroll
        for (int ni = 0; ni < 2; ++ni)
          acc[mi][ni] = __builtin_amdgcn_mfma_f32_16x16x32_bf16(
              a[mi], bfrag[kk][ni], acc[mi][ni], 0, 0, 0);
    }

    // ---- pack acc -> zt (flipped bf16, column-major) ----
    {
      unsigned* ztw = reinterpret_cast<unsigned*>(zt);
#pragma unroll
      for (int ni = 0; ni < 2; ++ni) {
        const int col = w * 32 + ni * 16 + l15;
        const int cb  = col * 35 + l4 * 2;
#pragma unroll
        for (int mi = 0; mi < 4; ++mi)
#pragma unroll
          for (int p = 0; p < 2; ++p) {
            unsigned tpk = pk2(acc[mi][ni][2 * p], acc[mi][ni][2 * p + 1]);
            unsigned mflip = 0x80008000u + ((tpk >> 15) & 0x00010001u) * 0x7FFFu;
            ztw[cb + mi * 8 + p] = tpk ^ mflip;
          }
      }
    }
    __syncthreads();   // zt visible; lx consumed

    // ---- issue next tile's x + vid loads (latency hidden by walk) ----
    float4 x0, x1, x2, x3;
    int vN = 0;
    if (more) {
      const float4* src =
          reinterpret_cast<const float4*>(x + (size_t)eidN * DIN + s8 * 16);
      x0 = src[0]; x1 = src[1]; x2 = src[2]; x3 = src[3];
      if (tid < 64) vN = vid[sidN];
    }

    // ---- walk zt(t): 2 threads per column, 32 rows each ----
    {
      const int col = tid & 255;
      const int h   = tid >> 8;
      const unsigned* zc = reinterpret_cast<const unsigned*>(&zt[col * 70 + h * 32]);
      unsigned curm = 0;
      bool first = true;
#pragma unroll
      for (int p = 0; p < 16; ++p) {
        const unsigned pr = zc[p];
#pragma unroll
        for (int j = 0; j < 2; ++j) {
          const unsigned val = j ? (pr >> 16) : (pr & 0xFFFFu);
          curm = val > curm ? val : curm;
          const int row = h * 32 + p * 2 + j;
          if ((emask >> row) & 1) {
            const int v = lvid[cur][row];
            const unsigned enc = flip32_from16(curm);
            unsigned* ad = zu + (size_t)v * DMID + col;
            if (row == 63 || (first && (h == 0 || contOpen))) atomicMax(ad, enc);
            else *ad = enc;
            curm = 0; first = false;
          }
        }
      }
      if (h == 0 && !((emask >> 31) & 1)) {  // trailing open run in top half
        const int v = lvid[cur][31];
        atomicMax(zu + (size_t)v * DMID + col, flip32_from16(curm));
      }
    }

    // ---- convert + write next tile to LDS ----
    if (more) {
      uint2 o0 = { pk2(x0.x, x0.y), pk2(x0.z, x0.w) };
      uint2 o1 = { pk2(x1.x, x1.y), pk2(x1.z, x1.w) };
      uint2 o2 = { pk2(x2.x, x2.y), pk2(x2.z, x2.w) };
      uint2 o3 = { pk2(x3.x, x3.y), pk2(x3.z, x3.w) };
      unsigned short* dst = &lx[row8 * 136 + s8 * 16];
      *reinterpret_cast<uint2*>(dst + 0)  = o0;
      *reinterpret_cast<uint2*>(dst + 4)  = o1;
      *reinterpret_cast<uint2*>(dst + 8)  = o2;
      *reinterpret_cast<uint2*>(dst + 12) = o3;
      if (tid < 64) lvid[cur ^ 1][tid] = vN;
    }
    __syncthreads();   // stage visible; walk complete before next pack
  }
}

// ---------------------------------------------------------------------------
// Kernel Y: Y = unflip(zu) @ W2b  (V x 128). Block 256, wave 2x2.
// ---------------------------------------------------------------------------
__global__ __launch_bounds__(256) void k_ymm(
    const unsigned* __restrict__ zu, const float* __restrict__ W2,
    float* __restrict__ Y, int ntiles) {
  extern __shared__ unsigned short sm[];
  unsigned short* w2bt = sm;               // [128][264]
  unsigned short* za   = sm + 128 * 264;   // [64][264]

  const int tid  = threadIdx.x;
  const int lane = tid & 63;
  const int w    = tid >> 6;
  const int wr   = w >> 1, wc = w & 1;
  const int l15  = lane & 15, l4 = lane >> 4;

  {
    const int n = tid & 127, kh = tid >> 7;
    for (int k = kh * 128; k < kh * 128 + 128; ++k)
      w2bt[n * 264 + k] = b16(W2[(size_t)(DIN + k) * DOUT + n]);
  }
  __syncthreads();

  for (int t = blockIdx.x; t < ntiles; t += gridDim.x) {
    {
      const int row = tid >> 2, q = tid & 3;
      const int v = t * 64 + row;
      unsigned short* dz = &za[row * 264 + q * 64];
      if (v < VNUM) {
        const uint4* sz = reinterpret_cast<const uint4*>(zu + (size_t)v * DMID + q * 64);
#pragma unroll
        for (int i = 0; i < 16; ++i) {
          uint4 m = sz[i];
          ushort4 o = { (unsigned short)(unflip_bits(m.x) >> 16),
                        (unsigned short)(unflip_bits(m.y) >> 16),
                        (unsigned short)(unflip_bits(m.z) >> 16),
                        (unsigned short)(unflip_bits(m.w) >> 16) };
          *reinterpret_cast<ushort4*>(dz + i * 4) = o;
        }
      } else {
        ushort4 zo = {0, 0, 0, 0};
#pragma unroll
        for (int i = 0; i < 16; ++i) *reinterpret_cast<ushort4*>(dz + i * 4) = zo;
      }
    }
    __syncthreads();

    f32x4 acc[2][4];
#pragma unroll
    for (int mi = 0; mi < 2; ++mi)
#pragma unroll
      for (int ni = 0; ni < 4; ++ni) acc[mi][ni] = (f32x4){0.f, 0.f, 0.f, 0.f};

#pragma unroll
    for (int kk = 0; kk < 8; ++kk) {
      bf16x8 a[2], b[4];
#pragma unroll
      for (int mi = 0; mi < 2; ++mi)
        a[mi] = *reinterpret_cast<const bf16x8*>(
            &za[(wr * 32 + mi * 16 + l15) * 264 + kk * 32 + l4 * 8]);
#pragma unroll
      for (int ni = 0; ni < 4; ++ni)
        b[ni] = *reinterpret_cast<const bf16x8*>(
            &w2bt[(wc * 64 + ni * 16 + l15) * 264 + kk * 32 + l4 * 8]);
#pragma unroll
      for (int mi = 0; mi < 2; ++mi)
#pragma unroll
        for (int ni = 0; ni < 4; ++ni)
          acc[mi][ni] = __builtin_amdgcn_mfma_f32_16x16x32_bf16(
              a[mi], b[ni], acc[mi][ni], 0, 0, 0);
    }

#pragma unroll
    for (int mi = 0; mi < 2; ++mi)
#pragma unroll
      for (int r = 0; r < 4; ++r) {
        const int v = t * 64 + wr * 32 + mi * 16 + l4 * 4 + r;
        if (v < VNUM) {
          float* o = Y + (size_t)v * DOUT + wc * 64 + l15;
#pragma unroll
          for (int ni = 0; ni < 4; ++ni) o[ni * 16] = acc[mi][ni][r];
        }
      }
    __syncthreads();
  }
}

// ---------------------------------------------------------------------------
// Kernel 2: out = x @ W2a + Y[vid]  (original edge order). Block 256, wave 2x2.
// ---------------------------------------------------------------------------
__global__ __launch_bounds__(256, 3) void k_gemm2(
    const float* __restrict__ x, const int* __restrict__ vid,
    const float* __restrict__ W2, const float* __restrict__ Y,
    float* __restrict__ out, int ntiles) {
  __shared__ unsigned short w2at[128 * 136];
  __shared__ unsigned short lx[64 * 136];
  __shared__ int lvid[64];

  const int tid  = threadIdx.x;
  const int lane = tid & 63;
  const int w    = tid >> 6;
  const int wr   = w >> 1, wc = w & 1;
  const int l15  = lane & 15, l4 = lane >> 4;

  {
    const int n = tid & 127, kh = tid >> 7;
    for (int k = kh * 64; k < kh * 64 + 64; ++k)
      w2at[n * 136 + k] = b16(W2[(size_t)k * DOUT + n]);
  }
  __syncthreads();

  for (int t = blockIdx.x; t < ntiles; t += gridDim.x) {
    {
      const int row = tid >> 2, q = tid & 3;
      const float4* sx =
          reinterpret_cast<const float4*>(x + (size_t)(t * 64 + row) * DIN + q * 32);
#pragma unroll
      for (int i = 0; i < 8; ++i) {
        float4 v = sx[i];
        uint2 o = { pk2(v.x, v.y), pk2(v.z, v.w) };
        *reinterpret_cast<uint2*>(&lx[row * 136 + q * 32 + i * 4]) = o;
      }
      if (tid < 64) lvid[tid] = vid[t * 64 + tid];
    }
    __syncthreads();

    f32x4 acc[2][4];
#pragma unroll
    for (int mi = 0; mi < 2; ++mi)
#pragma unroll
      for (int ni = 0; ni < 4; ++ni) acc[mi][ni] = (f32x4){0.f, 0.f, 0.f, 0.f};

#pragma unroll
    for (int kk = 0; kk < 4; ++kk) {
      bf16x8 a[2], b[4];
#pragma unroll
      for (int mi = 0; mi < 2; ++mi)
        a[mi] = *reinterpret_cast<const bf16x8*>(
            &lx[(wr * 32 + mi * 16 + l15) * 136 + kk * 32 + l4 * 8]);
#pragma unroll
      for (int ni = 0; ni < 4; ++ni)
        b[ni] = *reinterpret_cast<const bf16x8*>(
            &w2at[(wc * 64 + ni * 16 + l15) * 136 + kk * 32 + l4 * 8]);
#pragma unroll
      for (int mi = 0; mi < 2; ++mi)
#pragma unroll
        for (int ni = 0; ni < 4; ++ni)
          acc[mi][ni] = __builtin_amdgcn_mfma_f32_16x16x32_bf16(
              a[mi], b[ni], acc[mi][ni], 0, 0, 0);
    }

    // epilogue: + Y[vid], fp32 store
#pragma unroll
    for (int mi = 0; mi < 2; ++mi)
#pragma unroll
      for (int r = 0; r < 4; ++r) {
        const int row = wr * 32 + mi * 16 + l4 * 4 + r;
        const float* Yr = Y + (size_t)lvid[row] * DOUT + wc * 64 + l15;
        float* o = out + (size_t)(t * 64 + row) * DOUT + wc * 64 + l15;
#pragma unroll
        for (int ni = 0; ni < 4; ++ni) o[ni * 16] = acc[mi][ni][r] + Yr[ni * 16];
      }
    __syncthreads();
  }
}

// ---------------------------------------------------------------------------
extern "C" void kernel_launch(void* const* d_in, const int* in_sizes, int n_in,
                              void* d_out, int out_size, void* d_ws, size_t ws_size,
                              hipStream_t stream) {
  const float* x   = (const float*)d_in[0];
  const int*   vid = (const int*)d_in[1];
  const float* W1  = (const float*)d_in[2];
  const float* b1  = (const float*)d_in[3];
  const float* W2  = (const float*)d_in[4];
  float* out = (float*)d_out;

  const int E = in_sizes[1];      // 800000 (divisible by 64)
  const int ntiles = E / 64;
  const int ntY = (VNUM + 63) / 64;   // 782
  const int nb = (VNUM + 255) / 256;  // 196 scan blocks

  char* ws = (char*)d_ws;
  size_t off = 0;
  unsigned* zu = (unsigned*)(ws + off); off += (size_t)VNUM * DMID * 4;
  int* cnt     = (int*)(ws + off);      off += (size_t)VNUM * 4;
  int* sorted  = (int*)(ws + off);      off += (size_t)E * 4;
  float* Y     = (float*)(ws + off);    off += (size_t)VNUM * DOUT * 4;
  int* bsum    = (int*)(ws + off);      off += 256 * 4;

  hipMemsetAsync(zu, 0, (size_t)VNUM * DMID * 4 + VNUM * 4, stream);

  k_hist<<<(E + 255) / 256, 256, 0, stream>>>(vid, cnt, E);
  k_scan_red<<<nb, 256, 0, stream>>>(cnt, bsum, VNUM);
  k_scan_top<<<1, 256, 0, stream>>>(bsum, nb);
  k_scan_fix<<<nb, 256, 0, stream>>>(cnt, bsum, VNUM);
  k_scatter<<<(E + 255) / 256, 256, 0, stream>>>(vid, cnt, sorted, E);

  k_gemm1_max<<<2048, 512, 0, stream>>>(x, vid, sorted, W1, b1, zu, ntiles);

  const int smY = (128 * 264 + 64 * 264) * sizeof(unsigned short);
  hipFuncSetAttribute((const void*)k_ymm,
                      hipFuncAttributeMaxDynamicSharedMemorySize, smY);
  k_ymm<<<782, 256, smY, stream>>>(zu, W2, Y, ntY);

  k_gemm2<<<768, 256, 0, stream>>>(x, vid, W2, Y, out, ntiles);
}